// Round 13
// baseline (792.350 us; speedup 1.0000x reference)
//
#include <hip/hip_runtime.h>
#include <float.h>

#define BATCH 16
#define NPTS  65536
#define NP    64      // NUM_PATCHES
#define PS    32      // PATCH_SIZE
#define NSLICE 16
#define SLICE_PTS (NPTS / NSLICE)   // 4096
#define CAP   128     // accepts per (center, slice): E~50, hard bound via theta

// Selection math (FPS argmax, KNN top-32) is float64 on f32 inputs (products
// of f32 exact in f64 -> bit-identical to numpy f64 regardless of FMA), with
// numpy expression order: ((a+b)+c), d2 = (c2+p2) - 2*dot, contract(off).
// Keys: trunc-48-bit f64 ordering bits | 16-bit index -> (dist, idx) lex order.
// LESSON (R10): poll cross-WG values on the SAME path they're written
// (relaxed agent atomics); never poll a cacheable copy.
// LESSON (R8/R11): don't strangle VGPRs with launch_bounds.
// LESSON (R12): fusion tail = wait_last + work_last; shrink the work quantum
// (slice-WGs tracking fps group-by-group), not just the wait.

__device__ __forceinline__ unsigned long long enc64(double d) {
    unsigned long long u = (unsigned long long)__double_as_longlong(d);
    return u ^ ((u >> 63) ? 0xFFFFFFFFFFFFFFFFull : 0x8000000000000000ull);
}
__device__ __forceinline__ unsigned enc32(float f) {
    unsigned u = __float_as_uint(f);
    return u ^ ((u >> 31) ? 0xFFFFFFFFu : 0x80000000u);
}
__device__ __forceinline__ float dec32(unsigned e) {
    unsigned u = (e & 0x80000000u) ? (e ^ 0x80000000u) : ~e;
    return __uint_as_float(u);
}

#define SENT 0xFFFFFFFFFFFFFFFFull

__global__ __launch_bounds__(256, 2)
void fused_kernel(const float* __restrict__ pts,
                  float* __restrict__ centers,               // [16][64][3]
                  unsigned long long* __restrict__ slots,    // [16][63][16], zeroed
                  unsigned* __restrict__ done,               // [16][16], zeroed
                  unsigned long long* __restrict__ gkeys,    // [1024][16][32]
                  float* __restrict__ patches)               // [16][64][32][3]
{
    const int t    = threadIdx.x;
    const int lane = t & 63;
    const int wid  = t >> 6;

    __shared__ unsigned long long wbest[4];      // fps
    __shared__ unsigned long long skey[16];      // fps
    __shared__ unsigned pool[4][512];            // knn
    __shared__ float    theta4[4];               // knn
    __shared__ int      cnt4[4];                 // knn
    __shared__ unsigned idxbuf[4][CAP];          // knn
    __shared__ int      mergef;                  // knn

    if (blockIdx.x < 256) {
        // ================= FPS (R9-proven, ~117 us standalone) =============
#pragma clang fp contract(off)
        __builtin_amdgcn_s_setprio(3);   // win issue arbitration vs knn waves
        const int b  = blockIdx.x & 15;
        const int wg = blockIdx.x >> 4;
        const float* __restrict__ P = pts + (size_t)b * NPTS * 3;

        float x[16], y[16], z[16];
        double md[16];
        const int gi0 = wg * 4096 + t;
#pragma unroll
        for (int k = 0; k < 16; ++k) {
            int i = gi0 + (k << 8);
            x[k] = P[3*i+0]; y[k] = P[3*i+1]; z[k] = P[3*i+2];
            md[k] = DBL_MAX;
        }

        double cx = (double)P[0], cy = (double)P[1], cz = (double)P[2];
        if (wg == 0 && t == 0) {
            float* c0 = centers + b * (NP*3);
            c0[0] = P[0]; c0[1] = P[1]; c0[2] = P[2];
        }

        unsigned long long* slot_it = slots + (size_t)b * 63 * 16;

        for (int it = 0; it < NP - 1; ++it) {
            double bd = -1.0; int bi = 0;
#pragma unroll
            for (int k = 0; k < 16; ++k) {
                double dx = (double)x[k] - cx;
                double dy = (double)y[k] - cy;
                double dz = (double)z[k] - cz;
                double d  = (dx*dx + dy*dy) + dz*dz;   // numpy add order
                double m  = fmin(md[k], d);
                md[k] = m;
                if (m > bd) { bd = m; bi = gi0 + (k << 8); }
            }
            unsigned long long db  = (unsigned long long)__double_as_longlong(bd);
            unsigned long long key = 0x8000000000000000ull
                                   | (db & 0xFFFFFFFFFFFF0000ull)
                                   | (unsigned long long)((~bi) & 0xFFFF);
#pragma unroll
            for (int off = 32; off > 0; off >>= 1) {
                unsigned long long o = __shfl_xor(key, off, 64);
                if (o > key) key = o;
            }
            if ((t & 63) == 0) wbest[t >> 6] = key;
            __syncthreads();                                   // bar1
            if (t == 0) {
                unsigned long long k0 = wbest[0];
                if (wbest[1] > k0) k0 = wbest[1];
                if (wbest[2] > k0) k0 = wbest[2];
                if (wbest[3] > k0) k0 = wbest[3];
                __hip_atomic_store(slot_it + wg, k0, __ATOMIC_RELAXED, __HIP_MEMORY_SCOPE_AGENT);
            }
            if (t < 16) {
                unsigned long long v;
                v = __hip_atomic_load(slot_it + t, __ATOMIC_RELAXED, __HIP_MEMORY_SCOPE_AGENT);
                while (v == 0) {
                    __builtin_amdgcn_s_sleep(1);
                    v = __hip_atomic_load(slot_it + t, __ATOMIC_RELAXED, __HIP_MEMORY_SCOPE_AGENT);
                }
                skey[t] = v;
            }
            __syncthreads();                                   // bar2
            unsigned long long bk = skey[0];
#pragma unroll
            for (int j = 1; j < 16; ++j) if (skey[j] > bk) bk = skey[j];
            int sel = (int)((~bk) & 0xFFFFull);
            cx = (double)P[3*sel+0]; cy = (double)P[3*sel+1]; cz = (double)P[3*sel+2];
            if (wg == 0 && t == 0) {
                float* c = centers + b*(NP*3) + (it+1)*3;
                c[0] = P[3*sel+0]; c[1] = P[3*sel+1]; c[2] = P[3*sel+2];
            }
            slot_it += 16;
        }
        return;
    }

    // ============ KNN: WG = (batch b, slice s of 4096 pts) =================
    const int id = blockIdx.x - 256;     // 0..255
    const int b  = id & 15;              // XCD-local with fps of same batch
    const int s  = id >> 4;              // 0..15
    const float* __restrict__ P = pts + (size_t)b * NPTS * 3;
    const int sbase = s * SLICE_PTS;
    const float4* __restrict__ P4 = (const float4*)(P + 3 * sbase);

    for (int w = 0; w < 16; ++w) {
        // ---- poll centers 4w..4w+3 (per-wave, no LDS/barrier needed) ----
        float cxf[4], cyf[4], czf[4], c2f[4];
        {
            int rnd = 4*w - 1 + (lane >> 4);
            unsigned long long key;
            if (rnd >= 0) {
                const unsigned long long* sp = slots + ((size_t)b*63 + rnd)*16 + (lane & 15);
                unsigned long long v = __hip_atomic_load(sp, __ATOMIC_RELAXED, __HIP_MEMORY_SCOPE_AGENT);
                while (v == 0) {
                    __builtin_amdgcn_s_sleep(8);
                    v = __hip_atomic_load(sp, __ATOMIC_RELAXED, __HIP_MEMORY_SCOPE_AGENT);
                }
                key = v;
            } else {
                key = 0xFFFFull;             // ~key & 0xFFFF == 0 -> sel = 0
            }
#pragma unroll
            for (int off = 1; off <= 8; off <<= 1) {   // max within 16-lane group
                unsigned long long o = __shfl_xor(key, off, 64);
                if (o > key) key = o;
            }
            int selv = (int)((~key) & 0xFFFFull);
            int sg[4];
            sg[0] = __shfl(selv,  0, 64);
            sg[1] = __shfl(selv, 16, 64);
            sg[2] = __shfl(selv, 32, 64);
            sg[3] = __shfl(selv, 48, 64);
#pragma unroll
            for (int g = 0; g < 4; ++g) {
                cxf[g] = P[3*sg[g]+0]; cyf[g] = P[3*sg[g]+1]; czf[g] = P[3*sg[g]+2];
                c2f[g] = cxf[g]*cxf[g] + cyf[g]*cyf[g] + czf[g]*czf[g];
            }
        }

        // ---- pass 1: per-thread top-2 over slice (16 pts/thread) ----
        float s0[4], s1[4];
#pragma unroll
        for (int g = 0; g < 4; ++g) { s0[g] = FLT_MAX; s1[g] = FLT_MAX; }
        for (int k = 0; k < SLICE_PTS/1024; ++k) {       // 4 iterations
            int vb = k*768 + 3*t;
            float4 A = P4[vb], B = P4[vb+1], C = P4[vb+2];
            float qx[4] = {A.x, A.w, B.z, C.y};
            float qy[4] = {A.y, B.x, B.w, C.z};
            float qz[4] = {A.z, B.y, C.x, C.w};
#pragma unroll
            for (int j = 0; j < 4; ++j) {
                float px = qx[j], py = qy[j], pz = qz[j];
                float p2 = px*px + py*py + pz*pz;
#pragma unroll
                for (int g = 0; g < 4; ++g) {
                    float dt = cxf[g]*px + cyf[g]*py + czf[g]*pz;
                    float d2 = (c2f[g] + p2) - 2.0f*dt;
                    float mx = fmaxf(d2, s0[g]);
                    s0[g] = fminf(s0[g], d2);
                    s1[g] = fminf(s1[g], mx);
                }
            }
        }
#pragma unroll
        for (int g = 0; g < 4; ++g) {
            pool[g][t]       = enc32(s0[g]);
            pool[g][256 + t] = enc32(s1[g]);
        }
        if (t < 4) cnt4[t] = 0;
        __syncthreads();                                 // bar A

        // ---- theta: wave wid -> 32nd smallest of pool[wid] (transposed) ----
        {
            const int g = wid;
            unsigned e[8];
#pragma unroll
            for (int j = 0; j < 8; ++j) e[j] = pool[g][j*64 + lane];
            unsigned ans = 0;
            for (int bit = 31; bit >= 0; --bit) {
                unsigned test = ans | ((1u << bit) - 1u);
                int cnt = 0;
#pragma unroll
                for (int j = 0; j < 8; ++j)
                    cnt += (int)__popcll(__ballot(e[j] <= test));
                if (cnt < 32) ans |= (1u << bit);
            }
            if (lane == 0) theta4[g] = dec32(ans) + 4.0e-3f;
        }
        __syncthreads();                                 // bar B
        float th[4];
#pragma unroll
        for (int g = 0; g < 4; ++g) th[g] = theta4[g];

        // ---- pass 2: rescan slice, record indices ----
        for (int k = 0; k < SLICE_PTS/1024; ++k) {
            int vb = k*768 + 3*t;
            float4 A = P4[vb], B = P4[vb+1], C = P4[vb+2];
            float qx[4] = {A.x, A.w, B.z, C.y};
            float qy[4] = {A.y, B.x, B.w, C.z};
            float qz[4] = {A.z, B.y, C.x, C.w};
            int ib = sbase + (k << 10) + (t << 2);
#pragma unroll
            for (int j = 0; j < 4; ++j) {
                float px = qx[j], py = qy[j], pz = qz[j];
                float p2 = px*px + py*py + pz*pz;
#pragma unroll
                for (int g = 0; g < 4; ++g) {
                    float dt = cxf[g]*px + cyf[g]*py + czf[g]*pz;
                    float d2 = (c2f[g] + p2) - 2.0f*dt;
                    bool hit = (d2 <= th[g]);
                    unsigned long long m = __ballot(hit);
                    if (m) {
                        int ldr = __ffsll(m) - 1;
                        int base = 0;
                        if (lane == ldr) base = atomicAdd(&cnt4[g], (int)__popcll(m));
                        base = __shfl(base, ldr, 64);
                        if (hit) {
                            int pos = base + (int)__popcll(m & ((1ull << lane) - 1ull));
                            if (pos < CAP) idxbuf[g][pos] = (unsigned)(ib + j);
                        }
                    }
                }
            }
        }
        __syncthreads();                                 // bar C

        // ---- phase 3: wave g -> exact f64 keys, slice top-32 -> gkeys ----
        {
            const int g = wid;
            int n = cnt4[g]; if (n > CAP) n = CAP;
            double cxd, cyd, czd, c2d;
            {
#pragma clang fp contract(off)
                cxd = (double)cxf[g]; cyd = (double)cyf[g]; czd = (double)czf[g];
                c2d = (cxd*cxd + cyd*cyd) + czd*czd;
            }
            unsigned long long rg[2];
#pragma unroll
            for (int j = 0; j < 2; ++j) {
                int p_ = lane + 64*j;
                if (p_ < n) {
                    unsigned i = idxbuf[g][p_];
                    double d2x;
                    {
#pragma clang fp contract(off)
                        double px_ = (double)P[3*i+0];
                        double py_ = (double)P[3*i+1];
                        double pz_ = (double)P[3*i+2];
                        double p2_ = (px_*px_ + py_*py_) + pz_*pz_;
                        double dt_ = (cxd*px_ + cyd*py_) + czd*pz_;
                        d2x = (c2d + p2_) - 2.0*dt_;
                    }
                    rg[j] = (enc64(d2x) & 0xFFFFFFFFFFFF0000ull)
                          | (unsigned long long)(i & 0xFFFF);
                } else rg[j] = SENT;
            }
            const int c = b * NP + w * 4 + g;
            unsigned long long okey = SENT;
            for (int r = 0; r < PS; ++r) {
                unsigned long long mn = (rg[0] < rg[1]) ? rg[0] : rg[1];
                int mp = (rg[0] < rg[1]) ? 0 : 1;
                unsigned long long wm = mn;
#pragma unroll
                for (int off = 32; off > 0; off >>= 1) {
                    unsigned long long o = __shfl_xor(wm, off, 64);
                    if (o < wm) wm = o;
                }
                if (wm == mn) { if (mp == 0) rg[0] = SENT; else rg[1] = SENT; }
                if (lane == r) okey = wm;
            }
            if (lane < PS)
                gkeys[((size_t)c * NSLICE + s) * PS + lane] = okey;
        }

        // ---- done-counter; 16th arriver merges this group's 4 centers ----
        __syncthreads();                                 // bar D (drains stores)
        if (t == 0) {
            unsigned old = __hip_atomic_fetch_add(&done[b * 16 + w], 1u,
                                                  __ATOMIC_ACQ_REL, __HIP_MEMORY_SCOPE_AGENT);
            mergef = (old == NSLICE - 1) ? 1 : 0;
        }
        __syncthreads();                                 // bar E
        if (mergef) {
            const int g = wid;
            const int c = b * NP + w * 4 + g;
            unsigned long long rg[8];
#pragma unroll
            for (int j = 0; j < 8; ++j)
                rg[j] = gkeys[(size_t)c * (NSLICE*PS) + j*64 + lane];

            unsigned long long okey = SENT;
            for (int r = 0; r < PS; ++r) {
                unsigned long long mn = rg[0]; int mp = 0;
#pragma unroll
                for (int j = 1; j < 8; ++j) if (rg[j] < mn) { mn = rg[j]; mp = j; }
                unsigned long long wm = mn;
#pragma unroll
                for (int off = 32; off > 0; off >>= 1) {
                    unsigned long long o = __shfl_xor(wm, off, 64);
                    if (o < wm) wm = o;
                }
                if (wm == mn) {
#pragma unroll
                    for (int j = 0; j < 8; ++j) if (j == mp) rg[j] = SENT;
                }
                if (lane == r) okey = wm;
            }
            if (lane < PS) {
                int i = (int)(okey & 0xFFFFull);
                float* o = patches + (((size_t)c * PS) + lane) * 3;
                o[0] = P[3*i+0] - cxf[g];
                o[1] = P[3*i+1] - cyf[g];
                o[2] = P[3*i+2] - czf[g];
            }
        }
    }
}

extern "C" void kernel_launch(void* const* d_in, const int* in_sizes, int n_in,
                              void* d_out, int out_size, void* d_ws, size_t ws_size,
                              hipStream_t stream)
{
    const float* pts = (const float*)d_in[0];
    float* out      = (float*)d_out;
    float* patches  = out;                          // [16][64][32][3] = 98304
    float* centers  = out + (size_t)BATCH*NP*PS*3;  // [16][64][3]     = 3072

    unsigned long long* slots = (unsigned long long*)d_ws;                   // 129024 B
    unsigned* done            = (unsigned*)((char*)d_ws + 129024);           // 1 KB
    unsigned long long* gkeys = (unsigned long long*)((char*)d_ws + 131072); // 4 MB

    (void)hipMemsetAsync(d_ws, 0, 131072, stream);   // slots + done
    fused_kernel<<<dim3(512), dim3(256), 0, stream>>>(pts, centers, slots, done, gkeys, patches);
}